// Round 1
// baseline (367.826 us; speedup 1.0000x reference)
//
#include <hip/hip_runtime.h>
#include <hip/hip_bf16.h>

#define BQ 4
#define QN 8192
#define DD 256
#define LL 2
#define PP 8
#define H0c 128
#define W0c 128
#define H1c 64
#define W1c 64
#define NC 52          // 4 (ref_delta) + 32 (offsets) + 16 (attn logits)
#define EPSF 1e-5f

// ---------------- Kernel 1: transpose (B,D,H,W) fp32 -> (B,H,W,D) bf16 ----------------
__global__ __launch_bounds__(256) void transpose_cast(const float* __restrict__ in,
                                                      __hip_bfloat16* __restrict__ out,
                                                      int HW) {
    __shared__ float tile[32][33];
    int b   = blockIdx.z;
    int hw0 = blockIdx.x * 32;
    int c0  = blockIdx.y * 32;
    const float* inb = in + (size_t)b * DD * HW;
    __hip_bfloat16* outb = out + (size_t)b * DD * HW;
    int tx = threadIdx.x, ty = threadIdx.y;
#pragma unroll
    for (int j = 0; j < 32; j += 8)
        tile[ty + j][tx] = inb[(size_t)(c0 + ty + j) * HW + hw0 + tx];
    __syncthreads();
#pragma unroll
    for (int j = 0; j < 32; j += 8)
        outb[(size_t)(hw0 + ty + j) * DD + c0 + tx] = __float2bfloat16(tile[tx][ty + j]);
}

// ---------------- Kernel 2: projections q @ [Wrd|Woff|Wattn] + bias -> proj[32768][52] (fp32) ----------------
__global__ __launch_bounds__(256) void proj_kernel(const float* __restrict__ q,
                                                   const float* __restrict__ Wrd,
                                                   const float* __restrict__ brd,
                                                   const float* __restrict__ Woff,
                                                   const float* __restrict__ boff,
                                                   const float* __restrict__ Wattn,
                                                   const float* __restrict__ battn,
                                                   float* __restrict__ proj) {
    __shared__ float Ws[DD][NC];   // 53 KB
    __shared__ float bs[NC];
    int tid = threadIdx.x;
    for (int i = tid; i < DD * 4;  i += 256) Ws[i >> 2][(i & 3)]        = Wrd[i];
    for (int i = tid; i < DD * 32; i += 256) Ws[i >> 5][4 + (i & 31)]   = Woff[i];
    for (int i = tid; i < DD * 16; i += 256) Ws[i >> 4][36 + (i & 15)]  = Wattn[i];
    if (tid < 4)        bs[tid] = brd[tid];
    else if (tid < 36)  bs[tid] = boff[tid - 4];
    else if (tid < 52)  bs[tid] = battn[tid - 36];
    __syncthreads();

    int m = blockIdx.x * 64 + (tid >> 2);   // query row (4 threads per query)
    int g = tid & 3;
    int col0 = g * 13;
    const float* qrow = q + (size_t)m * DD;
    float acc[13];
#pragma unroll
    for (int c = 0; c < 13; c++) acc[c] = 0.f;
    for (int k = 0; k < DD; k++) {
        float qv = qrow[k];
#pragma unroll
        for (int c = 0; c < 13; c++) acc[c] += qv * Ws[k][col0 + c];
    }
    float* prow = proj + (size_t)m * NC;
#pragma unroll
    for (int c = 0; c < 13; c++) prow[col0 + c] = acc[c] + bs[col0 + c];
}

// ---------------- Kernel 3: per-query deformable sampling -> S[32768][256] (fp32) ----------------
__global__ __launch_bounds__(256) void sample_kernel(const __hip_bfloat16* __restrict__ mapT0,
                                                     const __hip_bfloat16* __restrict__ mapT1,
                                                     const float* __restrict__ proj,
                                                     const float* __restrict__ base_ref,
                                                     float* __restrict__ S) {
    __shared__ float pr[NC];
    __shared__ int   si[16][4];   // corner element offsets (channel-0 index)
    __shared__ float sw[16][3];   // wx, wy, attn
    int n   = blockIdx.x;         // global query index = b*QN + q
    int b   = n >> 13;            // QN = 8192
    int tid = threadIdx.x;

    if (tid < NC) pr[tid] = proj[(size_t)n * NC + tid];
    __syncthreads();

    if (tid < 16) {
        int l = tid >> 3;                      // level, s = l*P + p = tid
        // softmax over all 16 attn logits
        float mx = pr[36];
#pragma unroll
        for (int i = 1; i < 16; i++) mx = fmaxf(mx, pr[36 + i]);
        float sum = 0.f;
#pragma unroll
        for (int i = 0; i < 16; i++) sum += __expf(pr[36 + i] - mx);
        float a = __expf(pr[36 + tid] - mx) / sum;

        int W = l ? W1c : W0c;
        int H = l ? H1c : H0c;
        float Wf = (float)W, Hf = (float)H;

        float bx = base_ref[(b * LL + l) * 2 + 0];
        float by = base_ref[(b * LL + l) * 2 + 1];
        bx = fminf(fmaxf(bx, EPSF), 1.f - EPSF);
        by = fminf(fmaxf(by, EPSF), 1.f - EPSF);
        float lgx = logf(bx / (1.f - bx));
        float lgy = logf(by / (1.f - by));
        float refx = 1.f / (1.f + __expf(-(lgx + pr[l * 2 + 0])));
        float refy = 1.f / (1.f + __expf(-(lgy + pr[l * 2 + 1])));

        float offx = pr[4 + tid * 2 + 0];
        float offy = pr[4 + tid * 2 + 1];
        float locx = refx + offx / Wf;
        float locy = refy + offy / Hf;
        if (l == 1) locy = locy - floorf(locy);   // jnp.remainder(y, 1.0)

        float gx = locx * 2.f - 1.f;
        float gy = locy * 2.f - 1.f;
        float x = ((gx + 1.f) * Wf - 1.f) * 0.5f;
        float y = ((gy + 1.f) * Hf - 1.f) * 0.5f;
        x = fminf(fmaxf(x, 0.f), Wf - 1.f);
        y = fminf(fmaxf(y, 0.f), Hf - 1.f);
        float x0f = floorf(x), y0f = floorf(y);
        float wx = x - x0f, wy = y - y0f;
        int x0 = (int)x0f, y0 = (int)y0f;
        int x1 = min(x0 + 1, W - 1);
        int y1 = min(y0 + 1, H - 1);
        int rowb = b * H * W;
        si[tid][0] = ((rowb + y0 * W) + x0) * DD;
        si[tid][1] = ((rowb + y0 * W) + x1) * DD;
        si[tid][2] = ((rowb + y1 * W) + x0) * DD;
        si[tid][3] = ((rowb + y1 * W) + x1) * DD;
        sw[tid][0] = wx; sw[tid][1] = wy; sw[tid][2] = a;
    }
    __syncthreads();

    int c = tid;
    float acc = 0.f;
#pragma unroll
    for (int s = 0; s < 16; s++) {
        const __hip_bfloat16* mp = (s < 8) ? mapT0 : mapT1;
        float v00 = __bfloat162float(mp[si[s][0] + c]);
        float v01 = __bfloat162float(mp[si[s][1] + c]);
        float v10 = __bfloat162float(mp[si[s][2] + c]);
        float v11 = __bfloat162float(mp[si[s][3] + c]);
        float wx = sw[s][0], wy = sw[s][1], a = sw[s][2];
        float top = v00 * (1.f - wx) + v01 * wx;
        float bot = v10 * (1.f - wx) + v11 * wx;
        acc += a * (top * (1.f - wy) + bot * wy);
    }
    S[(size_t)n * DD + c] = acc;
}

// ---------------- Kernel 4: out = S @ Wout + bout (fp32, 64x64 tile) ----------------
__global__ __launch_bounds__(256) void out_gemm(const float* __restrict__ S,
                                                const float* __restrict__ Wout,
                                                const float* __restrict__ bout,
                                                float* __restrict__ out) {
    __shared__ float As[32][68];   // [k][m], stride 68 keeps float4 alignment
    __shared__ float Bs[32][64];   // [k][n]
    int tid = threadIdx.x;
    int tx = tid & 15, ty = tid >> 4;
    int m0 = blockIdx.y * 64, n0 = blockIdx.x * 64;
    float acc[4][4] = {};

    for (int kt = 0; kt < DD; kt += 32) {
#pragma unroll
        for (int j = 0; j < 8; j++) {
            int e = tid + 256 * j;
            int r = e >> 5, k = e & 31;
            As[k][r] = S[(size_t)(m0 + r) * DD + kt + k];
        }
#pragma unroll
        for (int j = 0; j < 8; j++) {
            int e = tid + 256 * j;
            int k = e >> 6, nn = e & 63;
            Bs[k][nn] = Wout[(size_t)(kt + k) * DD + n0 + nn];
        }
        __syncthreads();
#pragma unroll
        for (int k = 0; k < 32; k++) {
            const float4 a4 = *(const float4*)&As[k][ty * 4];
            const float4 b4 = *(const float4*)&Bs[k][tx * 4];
            acc[0][0] += a4.x * b4.x; acc[0][1] += a4.x * b4.y; acc[0][2] += a4.x * b4.z; acc[0][3] += a4.x * b4.w;
            acc[1][0] += a4.y * b4.x; acc[1][1] += a4.y * b4.y; acc[1][2] += a4.y * b4.z; acc[1][3] += a4.y * b4.w;
            acc[2][0] += a4.z * b4.x; acc[2][1] += a4.z * b4.y; acc[2][2] += a4.z * b4.z; acc[2][3] += a4.z * b4.w;
            acc[3][0] += a4.w * b4.x; acc[3][1] += a4.w * b4.y; acc[3][2] += a4.w * b4.z; acc[3][3] += a4.w * b4.w;
        }
        __syncthreads();
    }

    float4 bias = *(const float4*)&bout[n0 + tx * 4];
#pragma unroll
    for (int i = 0; i < 4; i++) {
        int m = m0 + ty * 4 + i;
        float4 v;
        v.x = acc[i][0] + bias.x;
        v.y = acc[i][1] + bias.y;
        v.z = acc[i][2] + bias.z;
        v.w = acc[i][3] + bias.w;
        *(float4*)&out[(size_t)m * DD + n0 + tx * 4] = v;
    }
}

// ---------------- launch ----------------
extern "C" void kernel_launch(void* const* d_in, const int* in_sizes, int n_in,
                              void* d_out, int out_size, void* d_ws, size_t ws_size,
                              hipStream_t stream) {
    const float* q        = (const float*)d_in[0];
    const float* map0     = (const float*)d_in[1];
    const float* map1     = (const float*)d_in[2];
    const float* base_ref = (const float*)d_in[3];
    const float* Wrd      = (const float*)d_in[4];
    const float* brd      = (const float*)d_in[5];
    const float* Woff     = (const float*)d_in[6];
    const float* boff     = (const float*)d_in[7];
    const float* Wattn    = (const float*)d_in[8];
    const float* battn    = (const float*)d_in[9];
    const float* Wout     = (const float*)d_in[10];
    const float* bout     = (const float*)d_in[11];
    float* out = (float*)d_out;

    // workspace layout
    char* ws = (char*)d_ws;
    __hip_bfloat16* mapT0 = (__hip_bfloat16*)ws;                       // 33,554,432 B
    __hip_bfloat16* mapT1 = (__hip_bfloat16*)(ws + 33554432);          //  8,388,608 B
    float*          proj  = (float*)(ws + 33554432 + 8388608);         //  6,815,744 B
    float*          Sbuf  = (float*)(ws + 33554432 + 8388608 + 6815744); // 33,554,432 B

    // 1. transpose+cast feature maps
    transpose_cast<<<dim3(H0c * W0c / 32, DD / 32, BQ), dim3(32, 8), 0, stream>>>(map0, mapT0, H0c * W0c);
    transpose_cast<<<dim3(H1c * W1c / 32, DD / 32, BQ), dim3(32, 8), 0, stream>>>(map1, mapT1, H1c * W1c);

    // 2. projections
    proj_kernel<<<dim3(BQ * QN / 64), dim3(256), 0, stream>>>(q, Wrd, brd, Woff, boff, Wattn, battn, proj);

    // 3. sampling
    sample_kernel<<<dim3(BQ * QN), dim3(256), 0, stream>>>(mapT0, mapT1, proj, base_ref, Sbuf);

    // 4. output projection
    out_gemm<<<dim3(DD / 64, BQ * QN / 64), dim3(256), 0, stream>>>(Sbuf, Wout, bout, out);
}

// Round 2
// 289.045 us; speedup vs baseline: 1.2726x; 1.2726x over previous
//
#include <hip/hip_runtime.h>
#include <hip/hip_bf16.h>

#define BQ 4
#define QN 8192
#define DD 256
#define LL 2
#define PP 8
#define H0c 128
#define W0c 128
#define H1c 64
#define W1c 64
#define NCP 64         // padded proj stride: 4 ref_delta + 32 offsets + 16 attn + 12 pad
#define EPSF 1e-5f

typedef __attribute__((ext_vector_type(8))) short short8;
typedef __attribute__((ext_vector_type(4))) float floatx4;

static __device__ __forceinline__ float bf2f(unsigned short u) {
    union { unsigned int u; float f; } x;
    x.u = ((unsigned int)u) << 16;
    return x.f;
}
static __device__ __forceinline__ unsigned short f2bf(float f) {
    __hip_bfloat16 h = __float2bfloat16(f);
    return __builtin_bit_cast(unsigned short, h);
}

// ---------------- Kernel 1: transpose (B,D,H,W) fp32 -> (B,H,W,D) bf16 ----------------
// Also reused for Wout (D=256, HW=256, B=1): WoutT[n][k] = Wout[k][n].
__global__ __launch_bounds__(256) void transpose_cast(const float* __restrict__ in,
                                                      __hip_bfloat16* __restrict__ out,
                                                      int HW) {
    __shared__ float tile[32][33];
    int b   = blockIdx.z;
    int hw0 = blockIdx.x * 32;
    int c0  = blockIdx.y * 32;
    const float* inb = in + (size_t)b * DD * HW;
    __hip_bfloat16* outb = out + (size_t)b * DD * HW;
    int tx = threadIdx.x, ty = threadIdx.y;
#pragma unroll
    for (int j = 0; j < 32; j += 8)
        tile[ty + j][tx] = inb[(size_t)(c0 + ty + j) * HW + hw0 + tx];
    __syncthreads();
#pragma unroll
    for (int j = 0; j < 32; j += 8)
        outb[(size_t)(hw0 + ty + j) * DD + c0 + tx] = __float2bfloat16(tile[tx][ty + j]);
}

// ---------------- Kernel 2: pack [Wrd|Woff|Wattn|0] -> Wall[256][64] fp32, biases -> bias64 ----------------
__global__ __launch_bounds__(256) void pack_wall(const float* __restrict__ Wrd, const float* __restrict__ brd,
                                                 const float* __restrict__ Woff, const float* __restrict__ boff,
                                                 const float* __restrict__ Wattn, const float* __restrict__ battn,
                                                 float* __restrict__ Wall, float* __restrict__ bias64) {
    int idx = blockIdx.x * 256 + threadIdx.x;   // 0..16383
    int k = idx >> 6, c = idx & 63;
    float v = (c < 4)  ? Wrd[k * 4 + c]
            : (c < 36) ? Woff[k * 32 + (c - 4)]
            : (c < 52) ? Wattn[k * 16 + (c - 36)]
            : 0.f;
    Wall[idx] = v;
    if (idx < 64) {
        float bv = (idx < 4)  ? brd[idx]
                 : (idx < 36) ? boff[idx - 4]
                 : (idx < 52) ? battn[idx - 36]
                 : 0.f;
        bias64[idx] = bv;
    }
}

// ---------------- Kernel 3: proj = q @ Wall + bias64 (fp32, 64x64 tile, N=64) ----------------
__global__ __launch_bounds__(256) void proj_gemm(const float* __restrict__ q,
                                                 const float* __restrict__ Wall,
                                                 const float* __restrict__ bias64,
                                                 float* __restrict__ proj) {
    __shared__ float As[32][68];
    __shared__ float Bs[32][64];
    int tid = threadIdx.x;
    int tx = tid & 15, ty = tid >> 4;
    int m0 = blockIdx.x * 64;
    float acc[4][4] = {};

    for (int kt = 0; kt < DD; kt += 32) {
#pragma unroll
        for (int j = 0; j < 8; j++) {
            int e = tid + 256 * j;
            int r = e >> 5, k = e & 31;
            As[k][r] = q[(size_t)(m0 + r) * DD + kt + k];
        }
#pragma unroll
        for (int j = 0; j < 2; j++) {
            int e = tid + 256 * j;
            int k = e >> 6, nn = e & 63;
            Bs[kt ? 0 : 0][0] = Bs[0][0]; // no-op to keep structure clear
            Bs[k + j * 0][nn] = Wall[(size_t)(kt + k) * 64 + nn];
        }
        // note: 32*64 = 2048 elems, 256 threads * 8 would overshoot; need 8 iters of k-span 4
#pragma unroll
        for (int j = 2; j < 8; j++) {
            int e = tid + 256 * j;
            int k = e >> 6, nn = e & 63;
            Bs[k][nn] = Wall[(size_t)(kt + k) * 64 + nn];
        }
        __syncthreads();
#pragma unroll
        for (int k = 0; k < 32; k++) {
            const float4 a4 = *(const float4*)&As[k][ty * 4];
            const float4 b4 = *(const float4*)&Bs[k][tx * 4];
            acc[0][0] += a4.x * b4.x; acc[0][1] += a4.x * b4.y; acc[0][2] += a4.x * b4.z; acc[0][3] += a4.x * b4.w;
            acc[1][0] += a4.y * b4.x; acc[1][1] += a4.y * b4.y; acc[1][2] += a4.y * b4.z; acc[1][3] += a4.y * b4.w;
            acc[2][0] += a4.z * b4.x; acc[2][1] += a4.z * b4.y; acc[2][2] += a4.z * b4.z; acc[2][3] += a4.z * b4.w;
            acc[3][0] += a4.w * b4.x; acc[3][1] += a4.w * b4.y; acc[3][2] += a4.w * b4.z; acc[3][3] += a4.w * b4.w;
        }
        __syncthreads();
    }

    float4 bias = *(const float4*)&bias64[tx * 4];
#pragma unroll
    for (int i = 0; i < 4; i++) {
        int m = m0 + ty * 4 + i;
        float4 v;
        v.x = acc[i][0] + bias.x;
        v.y = acc[i][1] + bias.y;
        v.z = acc[i][2] + bias.z;
        v.w = acc[i][3] + bias.w;
        *(float4*)&proj[(size_t)m * NCP + tx * 4] = v;
    }
}

// ---------------- Kernel 4: deformable sampling, 4 queries/block, 4 ch/thread -> S bf16 ----------------
__global__ __launch_bounds__(256) void sample_kernel(const unsigned short* __restrict__ mapT0,
                                                     const unsigned short* __restrict__ mapT1,
                                                     const float* __restrict__ proj,
                                                     const float* __restrict__ base_ref,
                                                     unsigned short* __restrict__ S) {
    __shared__ float pr[4][64];
    __shared__ int   si[4][16][4];   // corner element offsets (channel-0 index)
    __shared__ float sw[4][16][4];   // combined bilinear*attn weights w00,w01,w10,w11
    int n0  = blockIdx.x * 4;
    int tid = threadIdx.x;
    int ql  = tid >> 6;      // wave-uniform: local query 0..3
    int lx  = tid & 63;

    pr[ql][lx] = proj[(size_t)(n0 + ql) * NCP + lx];
    __syncthreads();

    if (tid < 64) {
        int qq = tid >> 4, s = tid & 15, l = s >> 3;
        int n = n0 + qq, b = n >> 13;            // QN = 8192
        const float* p = pr[qq];
        // softmax over 16 attn logits
        float mx = p[36];
#pragma unroll
        for (int i = 1; i < 16; i++) mx = fmaxf(mx, p[36 + i]);
        float sum = 0.f;
#pragma unroll
        for (int i = 0; i < 16; i++) sum += __expf(p[36 + i] - mx);
        float a = __expf(p[36 + s] - mx) / sum;

        int W = l ? W1c : W0c;
        int H = l ? H1c : H0c;
        float Wf = (float)W, Hf = (float)H;

        float bx = base_ref[(b * LL + l) * 2 + 0];
        float by = base_ref[(b * LL + l) * 2 + 1];
        bx = fminf(fmaxf(bx, EPSF), 1.f - EPSF);
        by = fminf(fmaxf(by, EPSF), 1.f - EPSF);
        float lgx = logf(bx / (1.f - bx));
        float lgy = logf(by / (1.f - by));
        float refx = 1.f / (1.f + __expf(-(lgx + p[l * 2 + 0])));
        float refy = 1.f / (1.f + __expf(-(lgy + p[l * 2 + 1])));

        float locx = refx + p[4 + s * 2 + 0] / Wf;
        float locy = refy + p[4 + s * 2 + 1] / Hf;
        if (l == 1) locy = locy - floorf(locy);   // jnp.remainder(y, 1.0)

        float gx = locx * 2.f - 1.f;
        float gy = locy * 2.f - 1.f;
        float x = ((gx + 1.f) * Wf - 1.f) * 0.5f;
        float y = ((gy + 1.f) * Hf - 1.f) * 0.5f;
        x = fminf(fmaxf(x, 0.f), Wf - 1.f);
        y = fminf(fmaxf(y, 0.f), Hf - 1.f);
        float x0f = floorf(x), y0f = floorf(y);
        float wx = x - x0f, wy = y - y0f;
        int x0 = (int)x0f, y0 = (int)y0f;
        int x1 = min(x0 + 1, W - 1);
        int y1 = min(y0 + 1, H - 1);
        int rowb = b * H * W;
        si[qq][s][0] = ((rowb + y0 * W) + x0) * DD;
        si[qq][s][1] = ((rowb + y0 * W) + x1) * DD;
        si[qq][s][2] = ((rowb + y1 * W) + x0) * DD;
        si[qq][s][3] = ((rowb + y1 * W) + x1) * DD;
        float omx = 1.f - wx, omy = 1.f - wy;
        sw[qq][s][0] = a * omx * omy;
        sw[qq][s][1] = a * wx  * omy;
        sw[qq][s][2] = a * omx * wy;
        sw[qq][s][3] = a * wx  * wy;
    }
    __syncthreads();

    int c4 = lx * 4;
    float acc0 = 0.f, acc1 = 0.f, acc2 = 0.f, acc3 = 0.f;
#pragma unroll
    for (int s = 0; s < 16; s++) {
        const unsigned short* m = (s < 8) ? mapT0 : mapT1;
        int i0 = si[ql][s][0], i1 = si[ql][s][1], i2 = si[ql][s][2], i3 = si[ql][s][3];
        float w00 = sw[ql][s][0], w01 = sw[ql][s][1], w10 = sw[ql][s][2], w11 = sw[ql][s][3];
        ushort4 u00 = *(const ushort4*)(m + i0 + c4);
        ushort4 u01 = *(const ushort4*)(m + i1 + c4);
        ushort4 u10 = *(const ushort4*)(m + i2 + c4);
        ushort4 u11 = *(const ushort4*)(m + i3 + c4);
        acc0 += w00 * bf2f(u00.x) + w01 * bf2f(u01.x) + w10 * bf2f(u10.x) + w11 * bf2f(u11.x);
        acc1 += w00 * bf2f(u00.y) + w01 * bf2f(u01.y) + w10 * bf2f(u10.y) + w11 * bf2f(u11.y);
        acc2 += w00 * bf2f(u00.z) + w01 * bf2f(u01.z) + w10 * bf2f(u10.z) + w11 * bf2f(u11.z);
        acc3 += w00 * bf2f(u00.w) + w01 * bf2f(u01.w) + w10 * bf2f(u10.w) + w11 * bf2f(u11.w);
    }
    ushort4 o;
    o.x = f2bf(acc0); o.y = f2bf(acc1); o.z = f2bf(acc2); o.w = f2bf(acc3);
    *(ushort4*)(S + (size_t)(n0 + ql) * DD + c4) = o;
}

// ---------------- Kernel 5: out = S(bf16) @ WoutT(bf16)^T + bout via MFMA 16x16x32 ----------------
// A-frag: A[m=lane&15][k=quad*8+j]; B-frag: B[k=quad*8+j][n=lane&15] (fed from WoutT[n][k]);
// C/D: col=lane&15, row=quad*4+reg.
__global__ __launch_bounds__(256) void out_mfma(const unsigned short* __restrict__ S,
                                                const unsigned short* __restrict__ WT,
                                                const float* __restrict__ bout,
                                                float* __restrict__ out) {
    int wave = threadIdx.x >> 6, lane = threadIdx.x & 63;
    int m0 = blockIdx.x * 64 + wave * 16;
    int mrow = lane & 15, quad = lane >> 4;
    const unsigned short* Sp = S + (size_t)(m0 + mrow) * DD + quad * 8;

    floatx4 acc[16];
#pragma unroll
    for (int nt = 0; nt < 16; nt++) acc[nt] = {0.f, 0.f, 0.f, 0.f};

    for (int k0 = 0; k0 < DD; k0 += 32) {
        short8 a = *(const short8*)(Sp + k0);
#pragma unroll
        for (int nt = 0; nt < 16; nt++) {
            short8 b = *(const short8*)(WT + (size_t)(nt * 16 + mrow) * DD + k0 + quad * 8);
            acc[nt] = __builtin_amdgcn_mfma_f32_16x16x32_bf16(a, b, acc[nt], 0, 0, 0);
        }
    }

    int rbase = quad * 4;
#pragma unroll
    for (int nt = 0; nt < 16; nt++) {
        float bv = bout[nt * 16 + mrow];
#pragma unroll
        for (int r = 0; r < 4; r++) {
            out[(size_t)(m0 + rbase + r) * DD + nt * 16 + mrow] = acc[nt][r] + bv;
        }
    }
}

// ---------------- launch ----------------
extern "C" void kernel_launch(void* const* d_in, const int* in_sizes, int n_in,
                              void* d_out, int out_size, void* d_ws, size_t ws_size,
                              hipStream_t stream) {
    const float* q        = (const float*)d_in[0];
    const float* map0     = (const float*)d_in[1];
    const float* map1     = (const float*)d_in[2];
    const float* base_ref = (const float*)d_in[3];
    const float* Wrd      = (const float*)d_in[4];
    const float* brd      = (const float*)d_in[5];
    const float* Woff     = (const float*)d_in[6];
    const float* boff     = (const float*)d_in[7];
    const float* Wattn    = (const float*)d_in[8];
    const float* battn    = (const float*)d_in[9];
    const float* Wout     = (const float*)d_in[10];
    const float* bout     = (const float*)d_in[11];
    float* out = (float*)d_out;

    // workspace layout (bytes)
    char* ws = (char*)d_ws;
    __hip_bfloat16* mapT0  = (__hip_bfloat16*)(ws + 0);          // 33,554,432
    __hip_bfloat16* mapT1  = (__hip_bfloat16*)(ws + 33554432);   //  8,388,608
    __hip_bfloat16* WoutT  = (__hip_bfloat16*)(ws + 41943040);   //    131,072
    float*          Wall   = (float*)(ws + 42074112);            //     65,536
    float*          bias64 = (float*)(ws + 42139648);            //        256
    float*          proj   = (float*)(ws + 42139904);            //  8,388,608 (32768 x 64 fp32)
    unsigned short* Sbuf   = (unsigned short*)(ws + 50528512);   // 16,777,216 (32768 x 256 bf16)

    // 1. transpose+cast feature maps and Wout
    transpose_cast<<<dim3(H0c * W0c / 32, DD / 32, BQ), dim3(32, 8), 0, stream>>>(map0, mapT0, H0c * W0c);
    transpose_cast<<<dim3(H1c * W1c / 32, DD / 32, BQ), dim3(32, 8), 0, stream>>>(map1, mapT1, H1c * W1c);
    transpose_cast<<<dim3(DD / 32, DD / 32, 1), dim3(32, 8), 0, stream>>>(Wout, WoutT, DD);

    // 2. pack projection weights
    pack_wall<<<dim3(64), dim3(256), 0, stream>>>(Wrd, brd, Woff, boff, Wattn, battn, Wall, bias64);

    // 3. projections (fp32)
    proj_gemm<<<dim3(BQ * QN / 64), dim3(256), 0, stream>>>(q, Wall, bias64, proj);

    // 4. sampling (bf16 gathers, bf16 S out)
    sample_kernel<<<dim3(BQ * QN / 4), dim3(256), 0, stream>>>(
        (const unsigned short*)mapT0, (const unsigned short*)mapT1, proj, base_ref, Sbuf);

    // 5. output projection (bf16 MFMA)
    out_mfma<<<dim3(BQ * QN / 64), dim3(256), 0, stream>>>(
        Sbuf, (const unsigned short*)WoutT, bout, out);
}